// Round 1
// baseline (178.974 us; speedup 1.0000x reference)
//
#include <hip/hip_runtime.h>

#define F_EPS 1e-12f
#define F_DAMPING 0.95f
#define N_ITER 6
#define TPB 256
#define RPT 4
#define TILE (TPB * RPT)   // 1024 rays per tile
#define TILES 4            // tiles per block -> software pipeline depth

// Register-resident software-pipelined version.
//  - No LDS, no barriers: each thread loads its 4 rays directly as 3
//    consecutive float4 (48 B/lane). Per-instruction the wave spans 3 KB,
//    but the 3 instructions cover the same contiguous bytes -> identical
//    HBM traffic, L1 absorbs the re-touch.
//  - 4 tiles per block; the next tile's 6 loads are issued BEFORE computing
//    the current tile, so hipcc emits a counted vmcnt and the loads stay in
//    flight under ~2000 cycles of Newton compute (in-wave latency hiding
//    instead of convoy-phased TLP).
//  - Newton loop unchanged: it OUTER / ray INNER, hw rcp/rsq, explicit fmaf.
__launch_bounds__(TPB)
__global__ void trace_kernel(const float* __restrict__ P,
                             const float* __restrict__ V,
                             const float* __restrict__ tf,
                             const float* __restrict__ diameter,
                             const float* __restrict__ Cc,
                             const float* __restrict__ anchors,
                             const float* __restrict__ scale_p,
                             const unsigned char* __restrict__ normalize,
                             float* __restrict__ out,
                             int n)
{
    const int tid = threadIdx.x;

    // ---- uniform params (precise, contraction off; matches reference order) ----
    float R0,R1,R2,R3,R4,R5,R6,R7,R8, tv0,tv1,tv2;
    float C_eff, scale, half_d2, inv_s2;
    {
#pragma clang fp contract(off)
        float d  = diameter[0];
        float c  = Cc[0];
        float sc = scale_p[0];
        bool  nrm = (normalize[0] != 0);
        C_eff = nrm ? (c * 2.0f / d) : c;
        float s2 = sc * sc;
        float hr = d * 0.5f;
        half_d2 = hr * hr;
        float u = half_d2 / s2;
        float root = sqrtf(fmaxf(1.0f - (C_eff * C_eff) * u, F_EPS));
        float extent = sc * C_eff * u / (1.0f + root);
        float a0 = anchors[0], a1 = anchors[1];
        float dx0 = -a0 * extent;
        float dx1 = (a1 - a0) * extent;
        R0 = tf[0]; R1 = tf[1]; R2 = tf[2];
        R3 = tf[4]; R4 = tf[5]; R5 = tf[6];
        R6 = tf[8]; R7 = tf[9]; R8 = tf[10];
        tv0 = tf[0] * dx0 + tf[3];
        tv1 = tf[4] * dx0 + tf[7];
        tv2 = tf[8] * dx0 + tf[11];
        scale  = sc;
        inv_s2 = 1.0f / s2;
        if (blockIdx.x == 0 && tid < 16) {
            int i = tid >> 2, j = tid & 3;
            float v  = tf[tid];
            float sv = (j == 3) ? (tf[i * 4] * dx0 + v) : v;
            float nv = (j == 3) ? (tf[i * 4] * dx1 + v) : v;
            float* out_tail = out + (size_t)n * 5;
            out_tail[tid]      = sv;
            out_tail[16 + tid] = nv;
        }
    }
    const float ce2   = C_eff * C_eff;
    const float sC    = scale * C_eff;
    const float a_num = sC * inv_s2;          // F = a_num*r2/(1+root) - p.x
    const float ce2s  = ce2 * inv_s2;         // m = 1 - ce2s*r2
    const float Cs    = C_eff / scale;        // k = Cs * rsq(m)

    float* t_out = out;
    float* n_out = out + (size_t)n;
    float* v_out = out + (size_t)n * 4;

    const float4* P4 = reinterpret_cast<const float4*>(P);
    const float4* V4 = reinterpret_cast<const float4*>(V);
    float4*       N4 = reinterpret_cast<float4*>(n_out);

    const int total_full = n / TILE;          // number of full tiles
    const int tile0 = blockIdx.x * TILES;

    // ---- per-tile worker: 6 float4 in regs -> 4 rays -> outputs ----
    auto process = [&](float4 p0, float4 p1, float4 p2,
                       float4 q0, float4 q1, float4 q2, int tile) {
        float Px[4], Py[4], Pz[4], Vx[4], Vy[4], Vz[4];
        Px[0]=p0.x; Py[0]=p0.y; Pz[0]=p0.z; Px[1]=p0.w; Py[1]=p1.x; Pz[1]=p1.y;
        Px[2]=p1.z; Py[2]=p1.w; Pz[2]=p2.x; Px[3]=p2.y; Py[3]=p2.z; Pz[3]=p2.w;
        Vx[0]=q0.x; Vy[0]=q0.y; Vz[0]=q0.z; Vx[1]=q0.w; Vy[1]=q1.x; Vz[1]=q1.y;
        Vx[2]=q1.z; Vy[2]=q1.w; Vz[2]=q2.x; Vx[3]=q2.y; Vy[3]=q2.z; Vz[3]=q2.w;

        float Plx[4], Ply[4], Plz[4], vx[4], vy[4], vz[4], tN[4];
#pragma unroll
        for (int r = 0; r < 4; ++r) {
            float px0 = Px[r] - tv0, py0 = Py[r] - tv1, pz0 = Pz[r] - tv2;
            Plx[r] = px0 * R0 + py0 * R3 + pz0 * R6;
            Ply[r] = px0 * R1 + py0 * R4 + pz0 * R7;
            Plz[r] = px0 * R2 + py0 * R5 + pz0 * R8;
            vx[r] = Vx[r] * R0 + Vy[r] * R3 + Vz[r] * R6;
            vy[r] = Vx[r] * R1 + Vy[r] * R4 + Vz[r] * R7;
            vz[r] = Vx[r] * R2 + Vy[r] * R5 + Vz[r] * R8;
            float safe_vx = (fabsf(vx[r]) > F_EPS) ? vx[r] : F_EPS;
            tN[r] = (-Plx[r]) * __builtin_amdgcn_rcpf(safe_vx);
        }

#pragma unroll
        for (int it = 0; it < N_ITER; ++it) {
#pragma unroll
            for (int r = 0; r < 4; ++r) {
                float pxx = fmaf(tN[r], vx[r], Plx[r]);
                float py  = fmaf(tN[r], vy[r], Ply[r]);
                float pz  = fmaf(tN[r], vz[r], Plz[r]);
                float r2  = fmaf(py, py, pz * pz);
                float m   = fmaxf(fmaf(-ce2s, r2, 1.0f), F_EPS);
                float rsq = __builtin_amdgcn_rsqf(m);
                float root = m * rsq;
                float k    = Cs * rsq;
                float ird  = __builtin_amdgcn_rcpf(1.0f + root);
                float F    = fmaf(a_num * r2, ird, -pxx);
                float dF = fmaf(k * py, vy[r], fmaf(k * pz, vz[r], -vx[r]));
                dF = (fabsf(dF) > F_EPS) ? dF : F_EPS;
                tN[r] = fmaf(-F_DAMPING * F, __builtin_amdgcn_rcpf(dF), tN[r]);
            }
        }

        float tres[4], nxo[4], nyo[4], nzo[4], val[4];
#pragma unroll
        for (int r = 0; r < 4; ++r) {
            float pxx = fmaf(tN[r], vx[r], Plx[r]);
            float py  = fmaf(tN[r], vy[r], Ply[r]);
            float pz  = fmaf(tN[r], vz[r], Plz[r]);
            float r2  = fmaf(py, py, pz * pz);
            float m   = fmaxf(fmaf(-ce2s, r2, 1.0f), F_EPS);
            float rsq = __builtin_amdgcn_rsqf(m);
            float root = m * rsq;
            float k    = Cs * rsq;
            float ird  = __builtin_amdgcn_rcpf(1.0f + root);
            float F    = fmaf(a_num * r2, ird, -pxx);
            float gy = k * py, gz = k * pz;
            float nn2 = fmaf(gy, gy, fmaf(gz, gz, 1.0f));
            float irn = __builtin_amdgcn_rsqf(nn2);
            float nlx = -irn, nly = gy * irn, nlz = gz * irn;
            nxo[r] = nlx * R0 + nly * R1 + nlz * R2;
            nyo[r] = nlx * R3 + nly * R4 + nlz * R5;
            nzo[r] = nlx * R6 + nly * R7 + nlz * R8;
            tres[r] = tN[r];
            val[r]  = ((r2 <= half_d2) && (fabsf(F) < 1e-4f)) ? 1.0f : 0.0f;
        }

        int base = tile * TILE + 4 * tid;
        *reinterpret_cast<float4*>(t_out + base) = make_float4(tres[0], tres[1], tres[2], tres[3]);
        *reinterpret_cast<float4*>(v_out + base) = make_float4(val[0], val[1], val[2], val[3]);
        size_t f4 = (size_t)tile * (TILE * 3 / 4) + 3 * tid;
        N4[f4]     = make_float4(nxo[0], nyo[0], nzo[0], nxo[1]);
        N4[f4 + 1] = make_float4(nyo[1], nzo[1], nxo[2], nyo[2]);
        N4[f4 + 2] = make_float4(nzo[2], nxo[3], nyo[3], nzo[3]);
    };

    // ---- software-pipelined main loop over TILES tiles ----
    float4 c0, c1, c2, c3, c4, c5;   // current tile (P x3, V x3)
    float4 x0, x1, x2, x3, x4, x5;   // next tile

#define LOADT(T, a0, a1, a2, b0, b1, b2)                         \
    do {                                                         \
        size_t f4_ = (size_t)(T) * (TILE * 3 / 4) + 3 * tid;     \
        a0 = P4[f4_]; a1 = P4[f4_ + 1]; a2 = P4[f4_ + 2];        \
        b0 = V4[f4_]; b1 = V4[f4_ + 1]; b2 = V4[f4_ + 2];        \
    } while (0)

    if (tile0 < total_full) {
        LOADT(tile0, c0, c1, c2, c3, c4, c5);
#pragma unroll
        for (int k = 0; k < TILES; ++k) {
            int tile = tile0 + k;
            if (tile >= total_full) break;
            bool have_next = (k + 1 < TILES) && (tile + 1 < total_full);
            if (have_next) LOADT(tile + 1, x0, x1, x2, x3, x4, x5);
            process(c0, c1, c2, c3, c4, c5, tile);
            if (have_next) { c0 = x0; c1 = x1; c2 = x2; c3 = x3; c4 = x4; c5 = x5; }
        }
    }
#undef LOADT

    // ---- partial tail tile (scalar, guarded) ----
    const int rem = n - total_full * TILE;
    if (rem > 0 && total_full >= tile0 && total_full < tile0 + TILES) {
        const int start = total_full * TILE;
        for (int r = 0; r < RPT; ++r) {
            int i = start + tid * RPT + r;
            if (i >= n) break;
            float Pxs = P[(size_t)i * 3 + 0], Pys = P[(size_t)i * 3 + 1], Pzs = P[(size_t)i * 3 + 2];
            float Vxs = V[(size_t)i * 3 + 0], Vys = V[(size_t)i * 3 + 1], Vzs = V[(size_t)i * 3 + 2];
            float px0 = Pxs - tv0, py0 = Pys - tv1, pz0 = Pzs - tv2;
            float Plx = px0 * R0 + py0 * R3 + pz0 * R6;
            float Ply = px0 * R1 + py0 * R4 + pz0 * R7;
            float Plz = px0 * R2 + py0 * R5 + pz0 * R8;
            float vx = Vxs * R0 + Vys * R3 + Vzs * R6;
            float vy = Vxs * R1 + Vys * R4 + Vzs * R7;
            float vz = Vxs * R2 + Vys * R5 + Vzs * R8;
            float safe_vx = (fabsf(vx) > F_EPS) ? vx : F_EPS;
            float tN = (-Plx) * __builtin_amdgcn_rcpf(safe_vx);
#pragma unroll
            for (int it = 0; it < N_ITER; ++it) {
                float pxx = fmaf(tN, vx, Plx);
                float py  = fmaf(tN, vy, Ply);
                float pz  = fmaf(tN, vz, Plz);
                float r2  = fmaf(py, py, pz * pz);
                float m   = fmaxf(fmaf(-ce2s, r2, 1.0f), F_EPS);
                float rsq = __builtin_amdgcn_rsqf(m);
                float root = m * rsq;
                float k    = Cs * rsq;
                float ird  = __builtin_amdgcn_rcpf(1.0f + root);
                float F    = fmaf(a_num * r2, ird, -pxx);
                float dF = fmaf(k * py, vy, fmaf(k * pz, vz, -vx));
                dF = (fabsf(dF) > F_EPS) ? dF : F_EPS;
                tN = fmaf(-F_DAMPING * F, __builtin_amdgcn_rcpf(dF), tN);
            }
            float pxx = fmaf(tN, vx, Plx);
            float py  = fmaf(tN, vy, Ply);
            float pz  = fmaf(tN, vz, Plz);
            float r2  = fmaf(py, py, pz * pz);
            float m   = fmaxf(fmaf(-ce2s, r2, 1.0f), F_EPS);
            float rsq = __builtin_amdgcn_rsqf(m);
            float root = m * rsq;
            float k    = Cs * rsq;
            float ird  = __builtin_amdgcn_rcpf(1.0f + root);
            float F    = fmaf(a_num * r2, ird, -pxx);
            float gy = k * py, gz = k * pz;
            float nn2 = fmaf(gy, gy, fmaf(gz, gz, 1.0f));
            float irn = __builtin_amdgcn_rsqf(nn2);
            float nlx = -irn, nly = gy * irn, nlz = gz * irn;
            t_out[i] = tN;
            n_out[(size_t)i * 3 + 0] = nlx * R0 + nly * R1 + nlz * R2;
            n_out[(size_t)i * 3 + 1] = nlx * R3 + nly * R4 + nlz * R5;
            n_out[(size_t)i * 3 + 2] = nlx * R6 + nly * R7 + nlz * R8;
            v_out[i] = ((r2 <= half_d2) && (fabsf(F) < 1e-4f)) ? 1.0f : 0.0f;
        }
    }
}

extern "C" void kernel_launch(void* const* d_in, const int* in_sizes, int n_in,
                              void* d_out, int out_size, void* d_ws, size_t ws_size,
                              hipStream_t stream) {
    const float* P  = (const float*)d_in[0];
    const float* V  = (const float*)d_in[1];
    const float* tf = (const float*)d_in[2];
    const float* diameter = (const float*)d_in[3];
    const float* C  = (const float*)d_in[4];
    const float* anchors = (const float*)d_in[5];
    const float* scale = (const float*)d_in[6];
    const unsigned char* normalize = (const unsigned char*)d_in[7];
    int n = in_sizes[0] / 3;
    float* out = (float*)d_out;

    int total_tiles = (n + TILE - 1) / TILE;
    int blocks = (total_tiles + TILES - 1) / TILES;
    if (blocks < 1) blocks = 1;
    trace_kernel<<<blocks, TPB, 0, stream>>>(P, V, tf, diameter, C, anchors, scale,
                                             normalize, out, n);
}

// Round 2
// 178.513 us; speedup vs baseline: 1.0026x; 1.0026x over previous
//
#include <hip/hip_runtime.h>

#define F_EPS 1e-12f
#define F_DAMPING 0.95f
#define N_ITER 6
#define TPB 256
#define RPT 4
#define TILE (TPB * RPT)   // 1024 rays per tile
#define TILES 2            // tiles per block: depth-2 pipeline, 2048 blocks = 8/CU

// R2: same register-resident barrier-free pipeline as R1 (per-wave VALU duty
// measured ~96%), but TILES 4->2 so grid = 2048 blocks = 8 blocks/CU nominal
// (R1's 1024 blocks capped occupancy at 27.5% and throughput followed).
__launch_bounds__(TPB)
__global__ void trace_kernel(const float* __restrict__ P,
                             const float* __restrict__ V,
                             const float* __restrict__ tf,
                             const float* __restrict__ diameter,
                             const float* __restrict__ Cc,
                             const float* __restrict__ anchors,
                             const float* __restrict__ scale_p,
                             const unsigned char* __restrict__ normalize,
                             float* __restrict__ out,
                             int n)
{
    const int tid = threadIdx.x;

    // ---- uniform params (precise, contraction off; matches reference order) ----
    float R0,R1,R2,R3,R4,R5,R6,R7,R8, tv0,tv1,tv2;
    float C_eff, scale, half_d2, inv_s2;
    {
#pragma clang fp contract(off)
        float d  = diameter[0];
        float c  = Cc[0];
        float sc = scale_p[0];
        bool  nrm = (normalize[0] != 0);
        C_eff = nrm ? (c * 2.0f / d) : c;
        float s2 = sc * sc;
        float hr = d * 0.5f;
        half_d2 = hr * hr;
        float u = half_d2 / s2;
        float root = sqrtf(fmaxf(1.0f - (C_eff * C_eff) * u, F_EPS));
        float extent = sc * C_eff * u / (1.0f + root);
        float a0 = anchors[0], a1 = anchors[1];
        float dx0 = -a0 * extent;
        float dx1 = (a1 - a0) * extent;
        R0 = tf[0]; R1 = tf[1]; R2 = tf[2];
        R3 = tf[4]; R4 = tf[5]; R5 = tf[6];
        R6 = tf[8]; R7 = tf[9]; R8 = tf[10];
        tv0 = tf[0] * dx0 + tf[3];
        tv1 = tf[4] * dx0 + tf[7];
        tv2 = tf[8] * dx0 + tf[11];
        scale  = sc;
        inv_s2 = 1.0f / s2;
        if (blockIdx.x == 0 && tid < 16) {
            int i = tid >> 2, j = tid & 3;
            float v  = tf[tid];
            float sv = (j == 3) ? (tf[i * 4] * dx0 + v) : v;
            float nv = (j == 3) ? (tf[i * 4] * dx1 + v) : v;
            float* out_tail = out + (size_t)n * 5;
            out_tail[tid]      = sv;
            out_tail[16 + tid] = nv;
        }
    }
    const float ce2   = C_eff * C_eff;
    const float sC    = scale * C_eff;
    const float a_num = sC * inv_s2;          // F = a_num*r2/(1+root) - p.x
    const float ce2s  = ce2 * inv_s2;         // m = 1 - ce2s*r2
    const float Cs    = C_eff / scale;        // k = Cs * rsq(m)

    float* t_out = out;
    float* n_out = out + (size_t)n;
    float* v_out = out + (size_t)n * 4;

    const float4* P4 = reinterpret_cast<const float4*>(P);
    const float4* V4 = reinterpret_cast<const float4*>(V);
    float4*       N4 = reinterpret_cast<float4*>(n_out);

    const int total_full = n / TILE;          // number of full tiles
    const int tile0 = blockIdx.x * TILES;

    // ---- per-tile worker: 6 float4 in regs -> 4 rays -> outputs ----
    auto process = [&](float4 p0, float4 p1, float4 p2,
                       float4 q0, float4 q1, float4 q2, int tile) {
        float Px[4], Py[4], Pz[4], Vx[4], Vy[4], Vz[4];
        Px[0]=p0.x; Py[0]=p0.y; Pz[0]=p0.z; Px[1]=p0.w; Py[1]=p1.x; Pz[1]=p1.y;
        Px[2]=p1.z; Py[2]=p1.w; Pz[2]=p2.x; Px[3]=p2.y; Py[3]=p2.z; Pz[3]=p2.w;
        Vx[0]=q0.x; Vy[0]=q0.y; Vz[0]=q0.z; Vx[1]=q0.w; Vy[1]=q1.x; Vz[1]=q1.y;
        Vx[2]=q1.z; Vy[2]=q1.w; Vz[2]=q2.x; Vx[3]=q2.y; Vy[3]=q2.z; Vz[3]=q2.w;

        float Plx[4], Ply[4], Plz[4], vx[4], vy[4], vz[4], tN[4];
#pragma unroll
        for (int r = 0; r < 4; ++r) {
            float px0 = Px[r] - tv0, py0 = Py[r] - tv1, pz0 = Pz[r] - tv2;
            Plx[r] = px0 * R0 + py0 * R3 + pz0 * R6;
            Ply[r] = px0 * R1 + py0 * R4 + pz0 * R7;
            Plz[r] = px0 * R2 + py0 * R5 + pz0 * R8;
            vx[r] = Vx[r] * R0 + Vy[r] * R3 + Vz[r] * R6;
            vy[r] = Vx[r] * R1 + Vy[r] * R4 + Vz[r] * R7;
            vz[r] = Vx[r] * R2 + Vy[r] * R5 + Vz[r] * R8;
            float safe_vx = (fabsf(vx[r]) > F_EPS) ? vx[r] : F_EPS;
            tN[r] = (-Plx[r]) * __builtin_amdgcn_rcpf(safe_vx);
        }

#pragma unroll
        for (int it = 0; it < N_ITER; ++it) {
#pragma unroll
            for (int r = 0; r < 4; ++r) {
                float pxx = fmaf(tN[r], vx[r], Plx[r]);
                float py  = fmaf(tN[r], vy[r], Ply[r]);
                float pz  = fmaf(tN[r], vz[r], Plz[r]);
                float r2  = fmaf(py, py, pz * pz);
                float m   = fmaxf(fmaf(-ce2s, r2, 1.0f), F_EPS);
                float rsq = __builtin_amdgcn_rsqf(m);
                float root = m * rsq;
                float k    = Cs * rsq;
                float ird  = __builtin_amdgcn_rcpf(1.0f + root);
                float F    = fmaf(a_num * r2, ird, -pxx);
                float dF = fmaf(k * py, vy[r], fmaf(k * pz, vz[r], -vx[r]));
                dF = (fabsf(dF) > F_EPS) ? dF : F_EPS;
                tN[r] = fmaf(-F_DAMPING * F, __builtin_amdgcn_rcpf(dF), tN[r]);
            }
        }

        float tres[4], nxo[4], nyo[4], nzo[4], val[4];
#pragma unroll
        for (int r = 0; r < 4; ++r) {
            float pxx = fmaf(tN[r], vx[r], Plx[r]);
            float py  = fmaf(tN[r], vy[r], Ply[r]);
            float pz  = fmaf(tN[r], vz[r], Plz[r]);
            float r2  = fmaf(py, py, pz * pz);
            float m   = fmaxf(fmaf(-ce2s, r2, 1.0f), F_EPS);
            float rsq = __builtin_amdgcn_rsqf(m);
            float root = m * rsq;
            float k    = Cs * rsq;
            float ird  = __builtin_amdgcn_rcpf(1.0f + root);
            float F    = fmaf(a_num * r2, ird, -pxx);
            float gy = k * py, gz = k * pz;
            float nn2 = fmaf(gy, gy, fmaf(gz, gz, 1.0f));
            float irn = __builtin_amdgcn_rsqf(nn2);
            float nlx = -irn, nly = gy * irn, nlz = gz * irn;
            nxo[r] = nlx * R0 + nly * R1 + nlz * R2;
            nyo[r] = nlx * R3 + nly * R4 + nlz * R5;
            nzo[r] = nlx * R6 + nly * R7 + nlz * R8;
            tres[r] = tN[r];
            val[r]  = ((r2 <= half_d2) && (fabsf(F) < 1e-4f)) ? 1.0f : 0.0f;
        }

        int base = tile * TILE + 4 * tid;
        *reinterpret_cast<float4*>(t_out + base) = make_float4(tres[0], tres[1], tres[2], tres[3]);
        *reinterpret_cast<float4*>(v_out + base) = make_float4(val[0], val[1], val[2], val[3]);
        size_t f4 = (size_t)tile * (TILE * 3 / 4) + 3 * tid;
        N4[f4]     = make_float4(nxo[0], nyo[0], nzo[0], nxo[1]);
        N4[f4 + 1] = make_float4(nyo[1], nzo[1], nxo[2], nyo[2]);
        N4[f4 + 2] = make_float4(nzo[2], nxo[3], nyo[3], nzo[3]);
    };

    // ---- software-pipelined main loop over TILES tiles ----
    float4 c0, c1, c2, c3, c4, c5;   // current tile (P x3, V x3)
    float4 x0, x1, x2, x3, x4, x5;   // next tile

#define LOADT(T, a0, a1, a2, b0, b1, b2)                         \
    do {                                                         \
        size_t f4_ = (size_t)(T) * (TILE * 3 / 4) + 3 * tid;     \
        a0 = P4[f4_]; a1 = P4[f4_ + 1]; a2 = P4[f4_ + 2];        \
        b0 = V4[f4_]; b1 = V4[f4_ + 1]; b2 = V4[f4_ + 2];        \
    } while (0)

    if (tile0 < total_full) {
        LOADT(tile0, c0, c1, c2, c3, c4, c5);
#pragma unroll
        for (int k = 0; k < TILES; ++k) {
            int tile = tile0 + k;
            if (tile >= total_full) break;
            bool have_next = (k + 1 < TILES) && (tile + 1 < total_full);
            if (have_next) LOADT(tile + 1, x0, x1, x2, x3, x4, x5);
            process(c0, c1, c2, c3, c4, c5, tile);
            if (have_next) { c0 = x0; c1 = x1; c2 = x2; c3 = x3; c4 = x4; c5 = x5; }
        }
    }
#undef LOADT

    // ---- partial tail tile (scalar, guarded) ----
    const int rem = n - total_full * TILE;
    if (rem > 0 && total_full >= tile0 && total_full < tile0 + TILES) {
        const int start = total_full * TILE;
        for (int r = 0; r < RPT; ++r) {
            int i = start + tid * RPT + r;
            if (i >= n) break;
            float Pxs = P[(size_t)i * 3 + 0], Pys = P[(size_t)i * 3 + 1], Pzs = P[(size_t)i * 3 + 2];
            float Vxs = V[(size_t)i * 3 + 0], Vys = V[(size_t)i * 3 + 1], Vzs = V[(size_t)i * 3 + 2];
            float px0 = Pxs - tv0, py0 = Pys - tv1, pz0 = Pzs - tv2;
            float Plx = px0 * R0 + py0 * R3 + pz0 * R6;
            float Ply = px0 * R1 + py0 * R4 + pz0 * R7;
            float Plz = px0 * R2 + py0 * R5 + pz0 * R8;
            float vx = Vxs * R0 + Vys * R3 + Vzs * R6;
            float vy = Vxs * R1 + Vys * R4 + Vzs * R7;
            float vz = Vxs * R2 + Vys * R5 + Vzs * R8;
            float safe_vx = (fabsf(vx) > F_EPS) ? vx : F_EPS;
            float tN = (-Plx) * __builtin_amdgcn_rcpf(safe_vx);
#pragma unroll
            for (int it = 0; it < N_ITER; ++it) {
                float pxx = fmaf(tN, vx, Plx);
                float py  = fmaf(tN, vy, Ply);
                float pz  = fmaf(tN, vz, Plz);
                float r2  = fmaf(py, py, pz * pz);
                float m   = fmaxf(fmaf(-ce2s, r2, 1.0f), F_EPS);
                float rsq = __builtin_amdgcn_rsqf(m);
                float root = m * rsq;
                float k    = Cs * rsq;
                float ird  = __builtin_amdgcn_rcpf(1.0f + root);
                float F    = fmaf(a_num * r2, ird, -pxx);
                float dF = fmaf(k * py, vy, fmaf(k * pz, vz, -vx));
                dF = (fabsf(dF) > F_EPS) ? dF : F_EPS;
                tN = fmaf(-F_DAMPING * F, __builtin_amdgcn_rcpf(dF), tN);
            }
            float pxx = fmaf(tN, vx, Plx);
            float py  = fmaf(tN, vy, Ply);
            float pz  = fmaf(tN, vz, Plz);
            float r2  = fmaf(py, py, pz * pz);
            float m   = fmaxf(fmaf(-ce2s, r2, 1.0f), F_EPS);
            float rsq = __builtin_amdgcn_rsqf(m);
            float root = m * rsq;
            float k    = Cs * rsq;
            float ird  = __builtin_amdgcn_rcpf(1.0f + root);
            float F    = fmaf(a_num * r2, ird, -pxx);
            float gy = k * py, gz = k * pz;
            float nn2 = fmaf(gy, gy, fmaf(gz, gz, 1.0f));
            float irn = __builtin_amdgcn_rsqf(nn2);
            float nlx = -irn, nly = gy * irn, nlz = gz * irn;
            t_out[i] = tN;
            n_out[(size_t)i * 3 + 0] = nlx * R0 + nly * R1 + nlz * R2;
            n_out[(size_t)i * 3 + 1] = nlx * R3 + nly * R4 + nlz * R5;
            n_out[(size_t)i * 3 + 2] = nlx * R6 + nly * R7 + nlz * R8;
            v_out[i] = ((r2 <= half_d2) && (fabsf(F) < 1e-4f)) ? 1.0f : 0.0f;
        }
    }
}

extern "C" void kernel_launch(void* const* d_in, const int* in_sizes, int n_in,
                              void* d_out, int out_size, void* d_ws, size_t ws_size,
                              hipStream_t stream) {
    const float* P  = (const float*)d_in[0];
    const float* V  = (const float*)d_in[1];
    const float* tf = (const float*)d_in[2];
    const float* diameter = (const float*)d_in[3];
    const float* C  = (const float*)d_in[4];
    const float* anchors = (const float*)d_in[5];
    const float* scale = (const float*)d_in[6];
    const unsigned char* normalize = (const unsigned char*)d_in[7];
    int n = in_sizes[0] / 3;
    float* out = (float*)d_out;

    int total_tiles = (n + TILE - 1) / TILE;
    int blocks = (total_tiles + TILES - 1) / TILES;
    if (blocks < 1) blocks = 1;
    trace_kernel<<<blocks, TPB, 0, stream>>>(P, V, tf, diameter, C, anchors, scale,
                                             normalize, out, n);
}